// Round 5
// baseline (912.823 us; speedup 1.0000x reference)
//
#include <hip/hip_runtime.h>
#include <hip/hip_bf16.h>
#include <stdint.h>

// ============================================================================
// Attn_50233937494279: qb=q@Win^T; S=softmax(qb@c^T); ctx=S@c;
//                      out=tanh([ctx|qb]@Wout^T); returns (out[q,b,d], S[b,q,k])
//
// R5 (third submission of the R3 source; R3/R4 benches died at container
// ACQUISITION — empty timing dict, kernel never ran). R2 counters showed
// k-step time = MFMA-cyc + LDS-read-cyc (zero overlap; MfmaUtil 43%):
// per-CU/k-step MFMA 3725 cyc (768x 16x16x32 @4.85) + ds_read 3084 cyc
// (256KB @85B/cyc). Fix attacks both terms:
//   - MFMA shape 16x16x32 -> 32x32x16 (2495 vs 2176 TF ubench): 3725->3099 cyc;
//     per-wave tile 128x64 = 4x2 tiles of 32x32, acc[4][2] f32x16 (128 regs).
//   - Ah/Bh fragments held live across the mid-barrier (fah[2][4], fbh[2][2])
//     -> phase 2 no longer re-reads Ah: 32KB -> 24KB LDS read per wave/k-step.
//   - C/D layout (m74/m101): col=lane&31, row=(reg&3)+8*(reg>>2)+4*(lane>>5).
//     A/B operand: row/col=lane&31, 8-k chunk = lane>>5 (family analog of the
//     m89-verified 16x16x32 mapping).
// Pipeline skeleton unchanged from R2: ring-4 32KB slots, per k stage
// e0={Ah,Bh}, e1={Al,Bl}; vmcnt(4) top / vmcnt(8) mid; 2 barriers / 96 MFMA.
// SPLIT=0 (G4/G5): same shape switch, ring-4 depth-3, vmcnt(8/4/0).
//
// Precision: GEMM1/GEMM2 (pre-softmax) 3-term split-bf16; G4/G5 plain bf16.
// Workspace layout (200 MB), region reuse across stream-ordered phases:
//   A @ 0      (64MB): q_hi -> c_hi (after G1) -> p_bf16 (after G2)
//   B @ 64MB   (64MB): qb_hi+qb_lo -> ct (c transposed, after G2)
//   C @ 128MB  (64MB): cat = [ctx | qb] bf16
//   W @ 192MB  ( 8MB): Win_hi, Win_lo, Wout_bf16
//   d_out out-region (64MB, unused until G5): q_lo -> c_lo scratch
// ============================================================================

typedef __bf16 bf16x8 __attribute__((ext_vector_type(8)));
typedef float floatx16 __attribute__((ext_vector_type(16)));

__device__ __forceinline__ unsigned short f2bf_rne(float f) {
  unsigned int u = __float_as_uint(f);
  u += 0x7FFFu + ((u >> 16) & 1u);
  return (unsigned short)(u >> 16);
}
__device__ __forceinline__ float bf2f(unsigned short h) {
  return __uint_as_float(((unsigned int)h) << 16);
}

__device__ __forceinline__ void async_load16(const void* g, void* l) {
  __builtin_amdgcn_global_load_lds(
      (const __attribute__((address_space(1))) void*)g,
      (__attribute__((address_space(3))) void*)l,
      16, 0, 0);
}

// fragment LDS offset (shorts): row r, 8-k chunk kb, XOR-swizzled
__device__ __forceinline__ int frag_slot(int r, int kb) {
  return (r * 4 + (kb ^ ((r >> 1) & 3))) * 8;
}

// ----------------------------------------------------------------------------
// split fp32 -> bf16 hi/lo (lo==nullptr: plain convert). One float4 per thread.
// ----------------------------------------------------------------------------
__global__ __launch_bounds__(256) void split_kernel(
    const float* __restrict__ x, unsigned short* __restrict__ hi,
    unsigned short* __restrict__ lo, long n4)
{
  long i = (long)blockIdx.x * 256 + threadIdx.x;
  if (i >= n4) return;
  float4 v = ((const float4*)x)[i];
  ushort4 h;
  h.x = f2bf_rne(v.x); h.y = f2bf_rne(v.y);
  h.z = f2bf_rne(v.z); h.w = f2bf_rne(v.w);
  ((ushort4*)hi)[i] = h;
  if (lo) {
    ushort4 l;
    l.x = f2bf_rne(v.x - bf2f(h.x));
    l.y = f2bf_rne(v.y - bf2f(h.y));
    l.z = f2bf_rne(v.z - bf2f(h.z));
    l.w = f2bf_rne(v.w - bf2f(h.w));
    ((ushort4*)lo)[i] = l;
  }
}

// ----------------------------------------------------------------------------
// ct[b][d][k] = bf16(c[k][b][d]).  64x64 tiles via LDS.
// grid: (k_tiles=32, d_tiles=16, b=16)
// ----------------------------------------------------------------------------
__global__ __launch_bounds__(256) void transpose_kernel(
    const float* __restrict__ c, unsigned short* __restrict__ ct)
{
  __shared__ unsigned short t[64 * 68];
  int k0 = blockIdx.x * 64;
  int d0 = blockIdx.y * 64;
  int b  = blockIdx.z;
  int tid = threadIdx.x;
  #pragma unroll
  for (int p4 = 0; p4 < 4; ++p4) {
    int idx = p4 * 256 + tid;
    int kr = idx >> 4;
    int dc = (idx & 15) * 4;
    float4 v = *(const float4*)&c[(long)(k0 + kr) * 16384 + (long)b * 1024 + d0 + dc];
    ushort4 h;
    h.x = f2bf_rne(v.x); h.y = f2bf_rne(v.y);
    h.z = f2bf_rne(v.z); h.w = f2bf_rne(v.w);
    *(ushort4*)&t[kr * 68 + dc] = h;
  }
  __syncthreads();
  #pragma unroll
  for (int p4 = 0; p4 < 4; ++p4) {
    int idx = p4 * 256 + tid;
    int dr = idx >> 4;
    int kc = (idx & 15) * 4;
    ushort4 o;
    o.x = t[(kc + 0) * 68 + dr];
    o.y = t[(kc + 1) * 68 + dr];
    o.z = t[(kc + 2) * 68 + dr];
    o.w = t[(kc + 3) * 68 + dr];
    *(ushort4*)&ct[(long)b * 2097152 + (long)(d0 + dr) * 2048 + k0 + kc] = o;
  }
}

// ----------------------------------------------------------------------------
// row softmax over 2048 fp32 (in place) + bf16 copy for the ctx GEMM.
// one 256-thread block per row.
// ----------------------------------------------------------------------------
__global__ __launch_bounds__(256) void softmax_kernel(
    float* __restrict__ S, unsigned short* __restrict__ P)
{
  __shared__ float sred[8];
  long row = blockIdx.x;
  float* p = S + row * 2048;
  int tid = threadIdx.x;
  int lane = tid & 63, w = tid >> 6;
  float4 v0 = ((float4*)p)[tid];
  float4 v1 = ((float4*)p)[tid + 256];
  float m = fmaxf(fmaxf(fmaxf(v0.x, v0.y), fmaxf(v0.z, v0.w)),
                  fmaxf(fmaxf(v1.x, v1.y), fmaxf(v1.z, v1.w)));
  #pragma unroll
  for (int off = 32; off; off >>= 1) m = fmaxf(m, __shfl_xor(m, off));
  if (lane == 0) sred[w] = m;
  __syncthreads();
  m = fmaxf(fmaxf(sred[0], sred[1]), fmaxf(sred[2], sred[3]));
  v0.x = __expf(v0.x - m); v0.y = __expf(v0.y - m);
  v0.z = __expf(v0.z - m); v0.w = __expf(v0.w - m);
  v1.x = __expf(v1.x - m); v1.y = __expf(v1.y - m);
  v1.z = __expf(v1.z - m); v1.w = __expf(v1.w - m);
  float s = v0.x + v0.y + v0.z + v0.w + v1.x + v1.y + v1.z + v1.w;
  #pragma unroll
  for (int off = 32; off; off >>= 1) s += __shfl_xor(s, off);
  if (lane == 0) sred[4 + w] = s;
  __syncthreads();
  s = sred[4] + sred[5] + sred[6] + sred[7];
  float inv = 1.0f / s;
  v0.x *= inv; v0.y *= inv; v0.z *= inv; v0.w *= inv;
  v1.x *= inv; v1.y *= inv; v1.z *= inv; v1.w *= inv;
  ((float4*)p)[tid] = v0;
  ((float4*)p)[tid + 256] = v1;
  unsigned short* pp = P + row * 2048;
  ushort4 b0, b1;
  b0.x = f2bf_rne(v0.x); b0.y = f2bf_rne(v0.y);
  b0.z = f2bf_rne(v0.z); b0.w = f2bf_rne(v0.w);
  b1.x = f2bf_rne(v1.x); b1.y = f2bf_rne(v1.y);
  b1.z = f2bf_rne(v1.z); b1.w = f2bf_rne(v1.w);
  ((ushort4*)pp)[tid] = b0;
  ((ushort4*)pp)[tid + 256] = b1;
}

// ----------------------------------------------------------------------------
// Pipelined TN GEMM: C[bz][m][n] = sum_k A[bz][m][k] * B[bz][n][k]
// 256x256 block tile, 512 threads = 8 waves (2M x 4N), per-wave 128x64 via
// 4x2 tiles of v_mfma_f32_32x32x16_bf16 (acc[4][2] f32x16).
// LDS ring of 4 slots (slot = 16KB A-tile + 16KB B-tile), counted vmcnt.
// SPLIT=1: per k stage e0={Ah,Bh}@slot(2k)&3, e1={Al,Bl}@slot(2k+1)&3;
//          phase1 = hh (16 MFMA; fah/fbh stay live), phase2 = hl+lh (32 MFMA,
//          reads only Al/Bl). vmcnt(4) top / vmcnt(8) mid, 2 barriers/96 MFMA.
// SPLIT=0: plain bf16, ring-4 BK=32 depth-3 prefetch, vmcnt(8/4/0).
// LDS slot swizzle (0-conflict): slot = row*4 + (kb ^ ((row>>1)&3)).
// XCD swizzle: flat%8 = XCD; XCD owns an SM x SN sub-grid of 256-tiles
// (requires gridm = GM*SM, gridn = (8/GM)*SN); n varies fastest.
// MODE 0: fp32 C            MODE 1: bf16 C
// MODE 2: fp32 tanh, row m=(b*1024+q) remapped to out[(q*16+b)*1024+n]
// MODE 3: split write: P1/P2 = hi/lo at [m*1024+n]; Cp = cat bf16 at
//         [( (m&15)*1024 + (m>>4) )*2048 + 1024 + n]   (m = q*16+b)
// ----------------------------------------------------------------------------
template<int SPLIT, int MODE>
__global__ __launch_bounds__(512, 2) void gemm_kernel(
    const unsigned short* __restrict__ Ah, const unsigned short* __restrict__ Al,
    long sAb, long ldA,
    const unsigned short* __restrict__ Bh, const unsigned short* __restrict__ Bl,
    long sBb, long ldB,
    void* __restrict__ Cp, long sCb, long ldC,
    unsigned short* __restrict__ P1, unsigned short* __restrict__ P2,
    int K, int SM, int SN, int GM)
{
  // ring of 4 slots: A_r at r*8192 shorts (16KB), B_r at 32768+r*8192
  __shared__ __align__(16) unsigned short lds[65536];   // 128 KiB

  const int tid  = threadIdx.x;
  const int lane = tid & 63;
  const int w    = tid >> 6;      // 0..7
  const int wm   = w >> 2;        // 0..1
  const int wn   = w & 3;         // 0..3
  const int bz   = blockIdx.z;

  // XCD-aware remap (flat%8 assumed = XCD; locality-only heuristic)
  const int flat = blockIdx.x + gridDim.x * blockIdx.y;
  const int sub  = flat & 7;
  const int g    = flat >> 3;
  const long mt  = (long)(sub % GM) * SM + (g / SN);
  const long nt  = (long)(sub / GM) * SN + (g % SN);
  const long m0  = mt * 256;
  const long n0  = nt * 256;

  const unsigned short* a0 = Ah + bz * sAb + m0 * ldA;
  const unsigned short* a1 = SPLIT ? (Al + bz * sAb + m0 * ldA) : a0;
  const unsigned short* b0 = Bh + bz * sBb + n0 * ldB;
  const unsigned short* b1 = SPLIT ? (Bl + bz * sBb + n0 * ldB) : b0;

  // Staging geometry: per tile-operand 1024 16B-slots; 512 threads x 2 issues.
  // slot_linear s -> row = s>>2, stored k-slot kb = (s&3) ^ ((row>>1)&3);
  // global source is pre-swizzled so LDS dest stays linear (rule 21).
  const int s0r = tid >> 2,        s1r = (512 + tid) >> 2;
  const int s0k = (tid & 3) ^ ((s0r >> 1) & 3);
  const int s1k = ((512 + tid) & 3) ^ ((s1r >> 1) & 3);
  const long offA0 = (long)s0r * ldA + s0k * 8;
  const long offA1 = (long)s1r * ldA + s1k * 8;
  const long offB0 = (long)s0r * ldB + s0k * 8;
  const long offB1 = (long)s1r * ldB + s1k * 8;
  const int d0 = w * 512;          // wave-uniform LDS dest (shorts), issue 0
  const int d1 = 4096 + w * 512;   // issue 1

  floatx16 acc[4][2] = {};

  const int rA = wm * 128 + (lane & 31);   // A fragment row base (+ i*32)
  const int rB = wn * 64 + (lane & 31);    // B fragment row base (+ j*32)
  const int kbase = lane >> 5;             // 8-k chunk within a 16-k slice

  if constexpr (SPLIT) {
    // ---------------- two-phase unique-entry split pipeline ----------------
    const int nk = K / 32;

    auto stageE = [&](int k, int h) {    // h=0: {Ah,Bh}; h=1: {Al,Bl}
      const int slot = (2 * k + h) & 3;
      const unsigned short* As = h ? a1 : a0;
      const unsigned short* Bs = h ? b1 : b0;
      const long ks = (long)k * 32;
      const int ab = slot * 8192;
      const int bb = 32768 + slot * 8192;
      async_load16(As + offA0 + ks, &lds[ab + d0]);
      async_load16(As + offA1 + ks, &lds[ab + d1]);
      async_load16(Bs + offB0 + ks, &lds[bb + d0]);
      async_load16(Bs + offB1 + ks, &lds[bb + d1]);
    };

    stageE(0, 0); stageE(0, 1);          // prologue: 8 loads in flight

    for (int k = 0; k < nk; ++k) {
      // retire e0(k)={Ah,Bh}; keep e1(k) in flight
      asm volatile("s_waitcnt vmcnt(4)" ::: "memory");
      __builtin_amdgcn_s_barrier();
      __builtin_amdgcn_sched_barrier(0);

      if (k + 1 < nk) { stageE(k + 1, 0); stageE(k + 1, 1); }  // +8 in flight
      __builtin_amdgcn_sched_barrier(0);

      const unsigned short* Ah_t = &lds[((2 * k) & 3) * 8192];
      const unsigned short* Bh_t = &lds[32768 + ((2 * k) & 3) * 8192];
      const unsigned short* Al_t = &lds[((2 * k + 1) & 3) * 8192];
      const unsigned short* Bl_t = &lds[32768 + ((2 * k + 1) & 3) * 8192];

      // phase 1: hh — fah/fbh stay live through phase 2
      bf16x8 fah[2][4], fbh[2][2];
      __builtin_amdgcn_s_setprio(1);
      #pragma unroll
      for (int kk = 0; kk < 2; ++kk) {
        const int kb = kbase + kk * 2;
        #pragma unroll
        for (int j = 0; j < 2; ++j)
          fbh[kk][j] = *(const bf16x8*)&Bh_t[frag_slot(rB + j * 32, kb)];
        #pragma unroll
        for (int i = 0; i < 4; ++i)
          fah[kk][i] = *(const bf16x8*)&Ah_t[frag_slot(rA + i * 32, kb)];
        #pragma unroll
        for (int i = 0; i < 4; ++i) {
          acc[i][0] = __builtin_amdgcn_mfma_f32_32x32x16_bf16(fah[kk][i], fbh[kk][0], acc[i][0], 0, 0, 0);
          acc[i][1] = __builtin_amdgcn_mfma_f32_32x32x16_bf16(fah[kk][i], fbh[kk][1], acc[i][1], 0, 0, 0);
        }
      }
      __builtin_amdgcn_s_setprio(0);

      // retire e1(k)={Al,Bl}; keep e(k+1,*) in flight
      if (k + 1 < nk) asm volatile("s_waitcnt vmcnt(8)" ::: "memory");
      else            asm volatile("s_waitcnt vmcnt(0)" ::: "memory");
      __builtin_amdgcn_s_barrier();
      __builtin_amdgcn_sched_barrier(0);

      // phase 2: hl (Ah x Bl, fah live) + lh (Al x Bh, fbh live)
      __builtin_amdgcn_s_setprio(1);
      #pragma unroll
      for (int kk = 0; kk < 2; ++kk) {
        const int kb = kbase + kk * 2;
        bf16x8 fbl[2], fal[4];
        #pragma unroll
        for (int j = 0; j < 2; ++j)
          fbl[j] = *(const bf16x8*)&Bl_t[frag_slot(rB + j * 32, kb)];
        #pragma unroll
        for (int i = 0; i < 4; ++i)
          fal[i] = *(const bf16x8*)&Al_t[frag_slot(rA + i * 32, kb)];
        #pragma unroll
        for (int i = 0; i < 4; ++i) {
          acc[i][0] = __builtin_amdgcn_mfma_f32_32x32x16_bf16(fah[kk][i], fbl[0], acc[i][0], 0, 0, 0);
          acc[i][1] = __builtin_amdgcn_mfma_f32_32x32x16_bf16(fah[kk][i], fbl[1], acc[i][1], 0, 0, 0);
        }
        #pragma unroll
        for (int i = 0; i < 4; ++i) {
          acc[i][0] = __builtin_amdgcn_mfma_f32_32x32x16_bf16(fal[i], fbh[kk][0], acc[i][0], 0, 0, 0);
          acc[i][1] = __builtin_amdgcn_mfma_f32_32x32x16_bf16(fal[i], fbh[kk][1], acc[i][1], 0, 0, 0);
        }
      }
      __builtin_amdgcn_s_setprio(0);
    }
  } else {
    // ---------------- plain bf16 ring-4 depth-3 pipeline ------------------
    const int nkt = K / 32;

    auto stage = [&](int vt2) {
      const int slot = vt2 & 3;
      const long ks = (long)vt2 * 32;
      const int ab = slot * 8192;
      const int bb = 32768 + slot * 8192;
      async_load16(a0 + offA0 + ks, &lds[ab + d0]);
      async_load16(a0 + offA1 + ks, &lds[ab + d1]);
      async_load16(b0 + offB0 + ks, &lds[bb + d0]);
      async_load16(b0 + offB1 + ks, &lds[bb + d1]);
    };

    stage(0); stage(1); stage(2);

    for (int vt = 0; vt < nkt; ++vt) {
      const int ahead = nkt - 1 - vt;
      if (ahead >= 2)      asm volatile("s_waitcnt vmcnt(8)" ::: "memory");
      else if (ahead == 1) asm volatile("s_waitcnt vmcnt(4)" ::: "memory");
      else                 asm volatile("s_waitcnt vmcnt(0)" ::: "memory");
      __builtin_amdgcn_s_barrier();
      __builtin_amdgcn_sched_barrier(0);

      if (vt + 3 < nkt) stage(vt + 3);
      __builtin_amdgcn_sched_barrier(0);

      const unsigned short* At = &lds[(vt & 3) * 8192];
      const unsigned short* Bt = &lds[32768 + (vt & 3) * 8192];

      __builtin_amdgcn_s_setprio(1);
      #pragma unroll
      for (int kk = 0; kk < 2; ++kk) {
        const int kb = kbase + kk * 2;
        bf16x8 fb[2], fa[4];
        #pragma unroll
        for (int j = 0; j < 2; ++j)
          fb[j] = *(const bf16x8*)&Bt[frag_slot(rB + j * 32, kb)];
        #pragma unroll
        for (int i = 0; i < 4; ++i)
          fa[i] = *(const bf16x8*)&At[frag_slot(rA + i * 32, kb)];
        #pragma unroll
        for (int i = 0; i < 4; ++i) {
          acc[i][0] = __builtin_amdgcn_mfma_f32_32x32x16_bf16(fa[i], fb[0], acc[i][0], 0, 0, 0);
          acc[i][1] = __builtin_amdgcn_mfma_f32_32x32x16_bf16(fa[i], fb[1], acc[i][1], 0, 0, 0);
        }
      }
      __builtin_amdgcn_s_setprio(0);
    }
  }

  // epilogue: 32x32 C/D layout col=lane&31, row=(reg&3)+8*(reg>>2)+4*(lane>>5)
  // [m74/m101-verified]
  #pragma unroll
  for (int i = 0; i < 4; ++i) {
    #pragma unroll
    for (int j = 0; j < 2; ++j) {
      #pragma unroll
      for (int t = 0; t < 16; ++t) {
        long rg = m0 + wm * 128 + i * 32 + (t & 3) + 8 * (t >> 2) + 4 * (lane >> 5);
        long cg = n0 + wn * 64 + j * 32 + (lane & 31);
        float v = acc[i][j][t];
        if (MODE == 0) {
          ((float*)Cp)[bz * sCb + rg * ldC + cg] = v;
        } else if (MODE == 1) {
          ((unsigned short*)Cp)[bz * sCb + rg * ldC + cg] = f2bf_rne(v);
        } else if (MODE == 2) {
          long qq = rg & 1023, bb = rg >> 10;
          ((float*)Cp)[(qq * 16 + bb) * 1024 + cg] = tanhf(v);
        } else {
          unsigned short hv = f2bf_rne(v);
          unsigned short lv = f2bf_rne(v - bf2f(hv));
          P1[rg * 1024 + cg] = hv;
          P2[rg * 1024 + cg] = lv;
          long bb = rg & 15, qq = rg >> 4;
          ((unsigned short*)Cp)[(bb * 1024 + qq) * 2048 + 1024 + cg] = hv;
        }
      }
    }
  }
}

// ============================================================================
extern "C" void kernel_launch(void* const* d_in, const int* in_sizes, int n_in,
                              void* d_out, int out_size, void* d_ws, size_t ws_size,
                              hipStream_t stream)
{
  const float* q    = (const float*)d_in[0];   // [1024,16,1024]
  const float* c    = (const float*)d_in[1];   // [2048,16,1024]
  const float* Win  = (const float*)d_in[2];   // [1024,1024]
  const float* Wout = (const float*)d_in[3];   // [1024,2048]

  char* ws = (char*)d_ws;
  const size_t MB = 1024u * 1024u;

  unsigned short* qh  = (unsigned short*)(ws);             // region A phase 1
  unsigned short* ch  = (unsigned short*)(ws);             // region A phase 2
  unsigned short* pb  = (unsigned short*)(ws);             // region A phase 3
  unsigned short* qbh = (unsigned short*)(ws + 64 * MB);   // region B phase 1
  unsigned short* qbl = (unsigned short*)(ws + 96 * MB);
  unsigned short* ct  = (unsigned short*)(ws + 64 * MB);   // region B phase 2
  unsigned short* cat = (unsigned short*)(ws + 128 * MB);  // region C
  unsigned short* Wh  = (unsigned short*)(ws + 192 * MB);
  unsigned short* Wl  = (unsigned short*)(ws + 194 * MB);
  unsigned short* Wo  = (unsigned short*)(ws + 196 * MB);

  unsigned short* ql  = (unsigned short*)d_out;            // out-region scratch
  unsigned short* cl  = (unsigned short*)d_out;            // out-region scratch
  float* out0  = (float*)d_out;                            // [1024,16,1024]
  float* score = (float*)d_out + 16777216;                 // [16,1024,2048]

  // phase 1: splits/converts needed by G1
  split_kernel<<<16384, 256, 0, stream>>>(q,    qh, ql,      4194304L);
  split_kernel<<<1024,  256, 0, stream>>>(Win,  Wh, Wl,      262144L);
  split_kernel<<<2048,  256, 0, stream>>>(Wout, Wo, nullptr, 524288L);

  // G1: qb = q @ Win^T  (split), M=16384 (rows q*16+b), N=1024, K=1024
  // tiles 64m x 4n; XCD sub-grid 8m x 4n
  gemm_kernel<1, 3><<<dim3(32, 8, 1), 512, 0, stream>>>(
      qh, ql, 0L, 1024L, Wh, Wl, 0L, 1024L,
      (void*)cat, 0L, 0L, qbh, qbl, 1024, 8, 4, 8);

  // phase 2: split c (q_hi/q_lo now dead)
  split_kernel<<<32768, 256, 0, stream>>>(c, ch, cl, 8388608L);

  // G2: logits[b][q][k] = qb[b,q,:] . c[k,b,:]  (split)
  // tiles 4m x 8n per batch; XCD sub-grid 2m x 2n (4MB hi+lo = one XCD L2)
  gemm_kernel<1, 0><<<dim3(4, 8, 16), 512, 0, stream>>>(
      qbh, qbl, 1024L, 16384L, ch, cl, 1024L, 16384L,
      (void*)score, 2097152L, 2048L, nullptr, nullptr, 1024, 2, 2, 2);

  // phase 3 (qb/c_hi/c_lo dead): transpose c, softmax in place
  transpose_kernel<<<dim3(32, 16, 16), 256, 0, stream>>>(c, ct);
  softmax_kernel<<<16384, 256, 0, stream>>>(score, pb);

  // G4: ctx[b][q][d] = P[b,q,:] . ct[b,d,:]  -> cat[...,0:1024] bf16
  // tiles 4m x 4n per batch; XCD sub-grid 1m x 2n
  gemm_kernel<0, 1><<<dim3(4, 4, 16), 512, 0, stream>>>(
      pb, nullptr, 2097152L, 2048L, ct, nullptr, 2097152L, 2048L,
      (void*)cat, 2097152L, 2048L, nullptr, nullptr, 2048, 1, 2, 4);

  // G5: out[(q*16+b)*1024+d] = tanh(cat[b*1024+q,:] . Wout[d,:])
  // tiles 64m x 4n; XCD sub-grid 8m x 4n
  gemm_kernel<0, 2><<<dim3(32, 8, 1), 512, 0, stream>>>(
      cat, nullptr, 0L, 2048L, Wo, nullptr, 0L, 2048L,
      (void*)out0, 0L, 0L, nullptr, nullptr, 2048, 8, 4, 8);

  (void)in_sizes; (void)n_in; (void)out_size; (void)ws_size;
}

// Round 6
// 902.984 us; speedup vs baseline: 1.0109x; 1.0109x over previous
//
#include <hip/hip_runtime.h>
#include <hip/hip_bf16.h>
#include <stdint.h>

// ============================================================================
// Attn_50233937494279: qb=q@Win^T; S=softmax(qb@c^T); ctx=S@c;
//                      out=tanh([ctx|qb]@Wout^T); returns (out[q,b,d], S[b,q,k])
//
// R5 -> R6: fix the bank conflict the 32x32 shape introduced (R5:
// SQ_LDS_BANK_CONFLICT 0 -> 1.26e7, gains eaten). Fragment reads now span
// 32 rows x 2 kb per wave (was 16 x 4); old perm(r)=(r>>1)&3 is invariant
// under r->r+8, so stride-8 lane groups (rows r,r+8,r+16,r+24, same kb) hit
// one 4-bank group = 4-way conflict. New perm(r)=((r>>1)^(r>>3))&3:
//   consecutive-8 rows -> 8 distinct groups; stride-8 rows -> 4 distinct
//   (x2 kb = 2-way, free per m136). Staging source pre-swizzle updated to
//   the same bijection. Everything else identical to R5.
//
// Carried from R5: 32x32x16 MFMA (acc[4][2] f32x16, per-wave 128x64);
// SPLIT=1 two-phase unique-entry pipeline (e0={Ah,Bh}, e1={Al,Bl}, ring-4
// 32KB slots, vmcnt(4) top / vmcnt(8) mid, 2 barriers / 96 MFMA, fah/fbh
// live across the mid-barrier); SPLIT=0 ring-4 depth-3 vmcnt(8/4/0).
//
// Precision: GEMM1/GEMM2 (pre-softmax) 3-term split-bf16; G4/G5 plain bf16.
// Workspace layout (200 MB), region reuse across stream-ordered phases:
//   A @ 0      (64MB): q_hi -> c_hi (after G1) -> p_bf16 (after G2)
//   B @ 64MB   (64MB): qb_hi+qb_lo -> ct (c transposed, after G2)
//   C @ 128MB  (64MB): cat = [ctx | qb] bf16
//   W @ 192MB  ( 8MB): Win_hi, Win_lo, Wout_bf16
//   d_out out-region (64MB, unused until G5): q_lo -> c_lo scratch
// ============================================================================

typedef __bf16 bf16x8 __attribute__((ext_vector_type(8)));
typedef float floatx16 __attribute__((ext_vector_type(16)));

__device__ __forceinline__ unsigned short f2bf_rne(float f) {
  unsigned int u = __float_as_uint(f);
  u += 0x7FFFu + ((u >> 16) & 1u);
  return (unsigned short)(u >> 16);
}
__device__ __forceinline__ float bf2f(unsigned short h) {
  return __uint_as_float(((unsigned int)h) << 16);
}

__device__ __forceinline__ void async_load16(const void* g, void* l) {
  __builtin_amdgcn_global_load_lds(
      (const __attribute__((address_space(1))) void*)g,
      (__attribute__((address_space(3))) void*)l,
      16, 0, 0);
}

// k-slot permutation per row: must vary under BOTH r->r+1 (consecutive lanes)
// and r->r+8 (stride-8 lane groups).  [R6 fix: add r>>3 term]
__device__ __forceinline__ int kperm(int r) {
  return ((r >> 1) ^ (r >> 3)) & 3;
}
// fragment LDS offset (shorts): row r, 8-k chunk kb, XOR-swizzled
__device__ __forceinline__ int frag_slot(int r, int kb) {
  return (r * 4 + (kb ^ kperm(r))) * 8;
}

// ----------------------------------------------------------------------------
// split fp32 -> bf16 hi/lo (lo==nullptr: plain convert). One float4 per thread.
// ----------------------------------------------------------------------------
__global__ __launch_bounds__(256) void split_kernel(
    const float* __restrict__ x, unsigned short* __restrict__ hi,
    unsigned short* __restrict__ lo, long n4)
{
  long i = (long)blockIdx.x * 256 + threadIdx.x;
  if (i >= n4) return;
  float4 v = ((const float4*)x)[i];
  ushort4 h;
  h.x = f2bf_rne(v.x); h.y = f2bf_rne(v.y);
  h.z = f2bf_rne(v.z); h.w = f2bf_rne(v.w);
  ((ushort4*)hi)[i] = h;
  if (lo) {
    ushort4 l;
    l.x = f2bf_rne(v.x - bf2f(h.x));
    l.y = f2bf_rne(v.y - bf2f(h.y));
    l.z = f2bf_rne(v.z - bf2f(h.z));
    l.w = f2bf_rne(v.w - bf2f(h.w));
    ((ushort4*)lo)[i] = l;
  }
}

// ----------------------------------------------------------------------------
// ct[b][d][k] = bf16(c[k][b][d]).  64x64 tiles via LDS.
// grid: (k_tiles=32, d_tiles=16, b=16)
// ----------------------------------------------------------------------------
__global__ __launch_bounds__(256) void transpose_kernel(
    const float* __restrict__ c, unsigned short* __restrict__ ct)
{
  __shared__ unsigned short t[64 * 68];
  int k0 = blockIdx.x * 64;
  int d0 = blockIdx.y * 64;
  int b  = blockIdx.z;
  int tid = threadIdx.x;
  #pragma unroll
  for (int p4 = 0; p4 < 4; ++p4) {
    int idx = p4 * 256 + tid;
    int kr = idx >> 4;
    int dc = (idx & 15) * 4;
    float4 v = *(const float4*)&c[(long)(k0 + kr) * 16384 + (long)b * 1024 + d0 + dc];
    ushort4 h;
    h.x = f2bf_rne(v.x); h.y = f2bf_rne(v.y);
    h.z = f2bf_rne(v.z); h.w = f2bf_rne(v.w);
    *(ushort4*)&t[kr * 68 + dc] = h;
  }
  __syncthreads();
  #pragma unroll
  for (int p4 = 0; p4 < 4; ++p4) {
    int idx = p4 * 256 + tid;
    int dr = idx >> 4;
    int kc = (idx & 15) * 4;
    ushort4 o;
    o.x = t[(kc + 0) * 68 + dr];
    o.y = t[(kc + 1) * 68 + dr];
    o.z = t[(kc + 2) * 68 + dr];
    o.w = t[(kc + 3) * 68 + dr];
    *(ushort4*)&ct[(long)b * 2097152 + (long)(d0 + dr) * 2048 + k0 + kc] = o;
  }
}

// ----------------------------------------------------------------------------
// row softmax over 2048 fp32 (in place) + bf16 copy for the ctx GEMM.
// one 256-thread block per row.
// ----------------------------------------------------------------------------
__global__ __launch_bounds__(256) void softmax_kernel(
    float* __restrict__ S, unsigned short* __restrict__ P)
{
  __shared__ float sred[8];
  long row = blockIdx.x;
  float* p = S + row * 2048;
  int tid = threadIdx.x;
  int lane = tid & 63, w = tid >> 6;
  float4 v0 = ((float4*)p)[tid];
  float4 v1 = ((float4*)p)[tid + 256];
  float m = fmaxf(fmaxf(fmaxf(v0.x, v0.y), fmaxf(v0.z, v0.w)),
                  fmaxf(fmaxf(v1.x, v1.y), fmaxf(v1.z, v1.w)));
  #pragma unroll
  for (int off = 32; off; off >>= 1) m = fmaxf(m, __shfl_xor(m, off));
  if (lane == 0) sred[w] = m;
  __syncthreads();
  m = fmaxf(fmaxf(sred[0], sred[1]), fmaxf(sred[2], sred[3]));
  v0.x = __expf(v0.x - m); v0.y = __expf(v0.y - m);
  v0.z = __expf(v0.z - m); v0.w = __expf(v0.w - m);
  v1.x = __expf(v1.x - m); v1.y = __expf(v1.y - m);
  v1.z = __expf(v1.z - m); v1.w = __expf(v1.w - m);
  float s = v0.x + v0.y + v0.z + v0.w + v1.x + v1.y + v1.z + v1.w;
  #pragma unroll
  for (int off = 32; off; off >>= 1) s += __shfl_xor(s, off);
  if (lane == 0) sred[4 + w] = s;
  __syncthreads();
  s = sred[4] + sred[5] + sred[6] + sred[7];
  float inv = 1.0f / s;
  v0.x *= inv; v0.y *= inv; v0.z *= inv; v0.w *= inv;
  v1.x *= inv; v1.y *= inv; v1.z *= inv; v1.w *= inv;
  ((float4*)p)[tid] = v0;
  ((float4*)p)[tid + 256] = v1;
  unsigned short* pp = P + row * 2048;
  ushort4 b0, b1;
  b0.x = f2bf_rne(v0.x); b0.y = f2bf_rne(v0.y);
  b0.z = f2bf_rne(v0.z); b0.w = f2bf_rne(v0.w);
  b1.x = f2bf_rne(v1.x); b1.y = f2bf_rne(v1.y);
  b1.z = f2bf_rne(v1.z); b1.w = f2bf_rne(v1.w);
  ((ushort4*)pp)[tid] = b0;
  ((ushort4*)pp)[tid + 256] = b1;
}

// ----------------------------------------------------------------------------
// Pipelined TN GEMM: C[bz][m][n] = sum_k A[bz][m][k] * B[bz][n][k]
// 256x256 block tile, 512 threads = 8 waves (2M x 4N), per-wave 128x64 via
// 4x2 tiles of v_mfma_f32_32x32x16_bf16 (acc[4][2] f32x16).
// LDS ring of 4 slots (slot = 16KB A-tile + 16KB B-tile), counted vmcnt.
// SPLIT=1: per k stage e0={Ah,Bh}@slot(2k)&3, e1={Al,Bl}@slot(2k+1)&3;
//          phase1 = hh (16 MFMA; fah/fbh stay live), phase2 = hl+lh (32 MFMA,
//          reads only Al/Bl). vmcnt(4) top / vmcnt(8) mid, 2 barriers/96 MFMA.
// SPLIT=0: plain bf16, ring-4 BK=32 depth-3 prefetch, vmcnt(8/4/0).
// LDS slot swizzle (R6): slot = row*4 + (kb ^ (((row>>1)^(row>>3))&3)).
// XCD swizzle: flat%8 = XCD; XCD owns an SM x SN sub-grid of 256-tiles
// (requires gridm = GM*SM, gridn = (8/GM)*SN); n varies fastest.
// MODE 0: fp32 C            MODE 1: bf16 C
// MODE 2: fp32 tanh, row m=(b*1024+q) remapped to out[(q*16+b)*1024+n]
// MODE 3: split write: P1/P2 = hi/lo at [m*1024+n]; Cp = cat bf16 at
//         [( (m&15)*1024 + (m>>4) )*2048 + 1024 + n]   (m = q*16+b)
// ----------------------------------------------------------------------------
template<int SPLIT, int MODE>
__global__ __launch_bounds__(512, 2) void gemm_kernel(
    const unsigned short* __restrict__ Ah, const unsigned short* __restrict__ Al,
    long sAb, long ldA,
    const unsigned short* __restrict__ Bh, const unsigned short* __restrict__ Bl,
    long sBb, long ldB,
    void* __restrict__ Cp, long sCb, long ldC,
    unsigned short* __restrict__ P1, unsigned short* __restrict__ P2,
    int K, int SM, int SN, int GM)
{
  // ring of 4 slots: A_r at r*8192 shorts (16KB), B_r at 32768+r*8192
  __shared__ __align__(16) unsigned short lds[65536];   // 128 KiB

  const int tid  = threadIdx.x;
  const int lane = tid & 63;
  const int w    = tid >> 6;      // 0..7
  const int wm   = w >> 2;        // 0..1
  const int wn   = w & 3;         // 0..3
  const int bz   = blockIdx.z;

  // XCD-aware remap (flat%8 assumed = XCD; locality-only heuristic)
  const int flat = blockIdx.x + gridDim.x * blockIdx.y;
  const int sub  = flat & 7;
  const int g    = flat >> 3;
  const long mt  = (long)(sub % GM) * SM + (g / SN);
  const long nt  = (long)(sub / GM) * SN + (g % SN);
  const long m0  = mt * 256;
  const long n0  = nt * 256;

  const unsigned short* a0 = Ah + bz * sAb + m0 * ldA;
  const unsigned short* a1 = SPLIT ? (Al + bz * sAb + m0 * ldA) : a0;
  const unsigned short* b0 = Bh + bz * sBb + n0 * ldB;
  const unsigned short* b1 = SPLIT ? (Bl + bz * sBb + n0 * ldB) : b0;

  // Staging geometry: per tile-operand 1024 16B-slots; 512 threads x 2 issues.
  // slot_linear s -> row = s>>2, stored k-slot kb = (s&3) ^ kperm(row);
  // global source is pre-swizzled so LDS dest stays linear (rule 21).
  const int s0r = tid >> 2,        s1r = (512 + tid) >> 2;
  const int s0k = (tid & 3) ^ kperm(s0r);
  const int s1k = ((512 + tid) & 3) ^ kperm(s1r);
  const long offA0 = (long)s0r * ldA + s0k * 8;
  const long offA1 = (long)s1r * ldA + s1k * 8;
  const long offB0 = (long)s0r * ldB + s0k * 8;
  const long offB1 = (long)s1r * ldB + s1k * 8;
  const int d0 = w * 512;          // wave-uniform LDS dest (shorts), issue 0
  const int d1 = 4096 + w * 512;   // issue 1

  floatx16 acc[4][2] = {};

  const int rA = wm * 128 + (lane & 31);   // A fragment row base (+ i*32)
  const int rB = wn * 64 + (lane & 31);    // B fragment row base (+ j*32)
  const int kbase = lane >> 5;             // 8-k chunk within a 16-k slice

  if constexpr (SPLIT) {
    // ---------------- two-phase unique-entry split pipeline ----------------
    const int nk = K / 32;

    auto stageE = [&](int k, int h) {    // h=0: {Ah,Bh}; h=1: {Al,Bl}
      const int slot = (2 * k + h) & 3;
      const unsigned short* As = h ? a1 : a0;
      const unsigned short* Bs = h ? b1 : b0;
      const long ks = (long)k * 32;
      const int ab = slot * 8192;
      const int bb = 32768 + slot * 8192;
      async_load16(As + offA0 + ks, &lds[ab + d0]);
      async_load16(As + offA1 + ks, &lds[ab + d1]);
      async_load16(Bs + offB0 + ks, &lds[bb + d0]);
      async_load16(Bs + offB1 + ks, &lds[bb + d1]);
    };

    stageE(0, 0); stageE(0, 1);          // prologue: 8 loads in flight

    for (int k = 0; k < nk; ++k) {
      // retire e0(k)={Ah,Bh}; keep e1(k) in flight
      asm volatile("s_waitcnt vmcnt(4)" ::: "memory");
      __builtin_amdgcn_s_barrier();
      __builtin_amdgcn_sched_barrier(0);

      if (k + 1 < nk) { stageE(k + 1, 0); stageE(k + 1, 1); }  // +8 in flight
      __builtin_amdgcn_sched_barrier(0);

      const unsigned short* Ah_t = &lds[((2 * k) & 3) * 8192];
      const unsigned short* Bh_t = &lds[32768 + ((2 * k) & 3) * 8192];
      const unsigned short* Al_t = &lds[((2 * k + 1) & 3) * 8192];
      const unsigned short* Bl_t = &lds[32768 + ((2 * k + 1) & 3) * 8192];

      // phase 1: hh — fah/fbh stay live through phase 2
      bf16x8 fah[2][4], fbh[2][2];
      __builtin_amdgcn_s_setprio(1);
      #pragma unroll
      for (int kk = 0; kk < 2; ++kk) {
        const int kb = kbase + kk * 2;
        #pragma unroll
        for (int j = 0; j < 2; ++j)
          fbh[kk][j] = *(const bf16x8*)&Bh_t[frag_slot(rB + j * 32, kb)];
        #pragma unroll
        for (int i = 0; i < 4; ++i)
          fah[kk][i] = *(const bf16x8*)&Ah_t[frag_slot(rA + i * 32, kb)];
        #pragma unroll
        for (int i = 0; i < 4; ++i) {
          acc[i][0] = __builtin_amdgcn_mfma_f32_32x32x16_bf16(fah[kk][i], fbh[kk][0], acc[i][0], 0, 0, 0);
          acc[i][1] = __builtin_amdgcn_mfma_f32_32x32x16_bf16(fah[kk][i], fbh[kk][1], acc[i][1], 0, 0, 0);
        }
      }
      __builtin_amdgcn_s_setprio(0);

      // retire e1(k)={Al,Bl}; keep e(k+1,*) in flight
      if (k + 1 < nk) asm volatile("s_waitcnt vmcnt(8)" ::: "memory");
      else            asm volatile("s_waitcnt vmcnt(0)" ::: "memory");
      __builtin_amdgcn_s_barrier();
      __builtin_amdgcn_sched_barrier(0);

      // phase 2: hl (Ah x Bl, fah live) + lh (Al x Bh, fbh live)
      __builtin_amdgcn_s_setprio(1);
      #pragma unroll
      for (int kk = 0; kk < 2; ++kk) {
        const int kb = kbase + kk * 2;
        bf16x8 fbl[2], fal[4];
        #pragma unroll
        for (int j = 0; j < 2; ++j)
          fbl[j] = *(const bf16x8*)&Bl_t[frag_slot(rB + j * 32, kb)];
        #pragma unroll
        for (int i = 0; i < 4; ++i)
          fal[i] = *(const bf16x8*)&Al_t[frag_slot(rA + i * 32, kb)];
        #pragma unroll
        for (int i = 0; i < 4; ++i) {
          acc[i][0] = __builtin_amdgcn_mfma_f32_32x32x16_bf16(fah[kk][i], fbl[0], acc[i][0], 0, 0, 0);
          acc[i][1] = __builtin_amdgcn_mfma_f32_32x32x16_bf16(fah[kk][i], fbl[1], acc[i][1], 0, 0, 0);
        }
        #pragma unroll
        for (int i = 0; i < 4; ++i) {
          acc[i][0] = __builtin_amdgcn_mfma_f32_32x32x16_bf16(fal[i], fbh[kk][0], acc[i][0], 0, 0, 0);
          acc[i][1] = __builtin_amdgcn_mfma_f32_32x32x16_bf16(fal[i], fbh[kk][1], acc[i][1], 0, 0, 0);
        }
      }
      __builtin_amdgcn_s_setprio(0);
    }
  } else {
    // ---------------- plain bf16 ring-4 depth-3 pipeline ------------------
    const int nkt = K / 32;

    auto stage = [&](int vt2) {
      const int slot = vt2 & 3;
      const long ks = (long)vt2 * 32;
      const int ab = slot * 8192;
      const int bb = 32768 + slot * 8192;
      async_load16(a0 + offA0 + ks, &lds[ab + d0]);
      async_load16(a0 + offA1 + ks, &lds[ab + d1]);
      async_load16(b0 + offB0 + ks, &lds[bb + d0]);
      async_load16(b0 + offB1 + ks, &lds[bb + d1]);
    };

    stage(0); stage(1); stage(2);

    for (int vt = 0; vt < nkt; ++vt) {
      const int ahead = nkt - 1 - vt;
      if (ahead >= 2)      asm volatile("s_waitcnt vmcnt(8)" ::: "memory");
      else if (ahead == 1) asm volatile("s_waitcnt vmcnt(4)" ::: "memory");
      else                 asm volatile("s_waitcnt vmcnt(0)" ::: "memory");
      __builtin_amdgcn_s_barrier();
      __builtin_amdgcn_sched_barrier(0);

      if (vt + 3 < nkt) stage(vt + 3);
      __builtin_amdgcn_sched_barrier(0);

      const unsigned short* At = &lds[(vt & 3) * 8192];
      const unsigned short* Bt = &lds[32768 + (vt & 3) * 8192];

      __builtin_amdgcn_s_setprio(1);
      #pragma unroll
      for (int kk = 0; kk < 2; ++kk) {
        const int kb = kbase + kk * 2;
        bf16x8 fb[2], fa[4];
        #pragma unroll
        for (int j = 0; j < 2; ++j)
          fb[j] = *(const bf16x8*)&Bt[frag_slot(rB + j * 32, kb)];
        #pragma unroll
        for (int i = 0; i < 4; ++i)
          fa[i] = *(const bf16x8*)&At[frag_slot(rA + i * 32, kb)];
        #pragma unroll
        for (int i = 0; i < 4; ++i) {
          acc[i][0] = __builtin_amdgcn_mfma_f32_32x32x16_bf16(fa[i], fb[0], acc[i][0], 0, 0, 0);
          acc[i][1] = __builtin_amdgcn_mfma_f32_32x32x16_bf16(fa[i], fb[1], acc[i][1], 0, 0, 0);
        }
      }
      __builtin_amdgcn_s_setprio(0);
    }
  }

  // epilogue: 32x32 C/D layout col=lane&31, row=(reg&3)+8*(reg>>2)+4*(lane>>5)
  // [m74/m101-verified]
  #pragma unroll
  for (int i = 0; i < 4; ++i) {
    #pragma unroll
    for (int j = 0; j < 2; ++j) {
      #pragma unroll
      for (int t = 0; t < 16; ++t) {
        long rg = m0 + wm * 128 + i * 32 + (t & 3) + 8 * (t >> 2) + 4 * (lane >> 5);
        long cg = n0 + wn * 64 + j * 32 + (lane & 31);
        float v = acc[i][j][t];
        if (MODE == 0) {
          ((float*)Cp)[bz * sCb + rg * ldC + cg] = v;
        } else if (MODE == 1) {
          ((unsigned short*)Cp)[bz * sCb + rg * ldC + cg] = f2bf_rne(v);
        } else if (MODE == 2) {
          long qq = rg & 1023, bb = rg >> 10;
          ((float*)Cp)[(qq * 16 + bb) * 1024 + cg] = tanhf(v);
        } else {
          unsigned short hv = f2bf_rne(v);
          unsigned short lv = f2bf_rne(v - bf2f(hv));
          P1[rg * 1024 + cg] = hv;
          P2[rg * 1024 + cg] = lv;
          long bb = rg & 15, qq = rg >> 4;
          ((unsigned short*)Cp)[(bb * 1024 + qq) * 2048 + 1024 + cg] = hv;
        }
      }
    }
  }
}

// ============================================================================
extern "C" void kernel_launch(void* const* d_in, const int* in_sizes, int n_in,
                              void* d_out, int out_size, void* d_ws, size_t ws_size,
                              hipStream_t stream)
{
  const float* q    = (const float*)d_in[0];   // [1024,16,1024]
  const float* c    = (const float*)d_in[1];   // [2048,16,1024]
  const float* Win  = (const float*)d_in[2];   // [1024,1024]
  const float* Wout = (const float*)d_in[3];   // [1024,2048]

  char* ws = (char*)d_ws;
  const size_t MB = 1024u * 1024u;

  unsigned short* qh  = (unsigned short*)(ws);             // region A phase 1
  unsigned short* ch  = (unsigned short*)(ws);             // region A phase 2
  unsigned short* pb  = (unsigned short*)(ws);             // region A phase 3
  unsigned short* qbh = (unsigned short*)(ws + 64 * MB);   // region B phase 1
  unsigned short* qbl = (unsigned short*)(ws + 96 * MB);
  unsigned short* ct  = (unsigned short*)(ws + 64 * MB);   // region B phase 2
  unsigned short* cat = (unsigned short*)(ws + 128 * MB);  // region C
  unsigned short* Wh  = (unsigned short*)(ws + 192 * MB);
  unsigned short* Wl  = (unsigned short*)(ws + 194 * MB);
  unsigned short* Wo  = (unsigned short*)(ws + 196 * MB);

  unsigned short* ql  = (unsigned short*)d_out;            // out-region scratch
  unsigned short* cl  = (unsigned short*)d_out;            // out-region scratch
  float* out0  = (float*)d_out;                            // [1024,16,1024]
  float* score = (float*)d_out + 16777216;                 // [16,1024,2048]

  // phase 1: splits/converts needed by G1
  split_kernel<<<16384, 256, 0, stream>>>(q,    qh, ql,      4194304L);
  split_kernel<<<1024,  256, 0, stream>>>(Win,  Wh, Wl,      262144L);
  split_kernel<<<2048,  256, 0, stream>>>(Wout, Wo, nullptr, 524288L);

  // G1: qb = q @ Win^T  (split), M=16384 (rows q*16+b), N=1024, K=1024
  // tiles 64m x 4n; XCD sub-grid 8m x 4n
  gemm_kernel<1, 3><<<dim3(32, 8, 1), 512, 0, stream>>>(
      qh, ql, 0L, 1024L, Wh, Wl, 0L, 1024L,
      (void*)cat, 0L, 0L, qbh, qbl, 1024, 8, 4, 8);

  // phase 2: split c (q_hi/q_lo now dead)
  split_kernel<<<32768, 256, 0, stream>>>(c, ch, cl, 8388608L);

  // G2: logits[b][q][k] = qb[b,q,:] . c[k,b,:]  (split)
  // tiles 4m x 8n per batch; XCD sub-grid 2m x 2n (4MB hi+lo = one XCD L2)
  gemm_kernel<1, 0><<<dim3(4, 8, 16), 512, 0, stream>>>(
      qbh, qbl, 1024L, 16384L, ch, cl, 1024L, 16384L,
      (void*)score, 2097152L, 2048L, nullptr, nullptr, 1024, 2, 2, 2);

  // phase 3 (qb/c_hi/c_lo dead): transpose c, softmax in place
  transpose_kernel<<<dim3(32, 16, 16), 256, 0, stream>>>(c, ct);
  softmax_kernel<<<16384, 256, 0, stream>>>(score, pb);

  // G4: ctx[b][q][d] = P[b,q,:] . ct[b,d,:]  -> cat[...,0:1024] bf16
  // tiles 4m x 4n per batch; XCD sub-grid 1m x 2n
  gemm_kernel<0, 1><<<dim3(4, 4, 16), 512, 0, stream>>>(
      pb, nullptr, 2097152L, 2048L, ct, nullptr, 2097152L, 2048L,
      (void*)cat, 2097152L, 2048L, nullptr, nullptr, 2048, 1, 2, 4);

  // G5: out[(q*16+b)*1024+d] = tanh(cat[b*1024+q,:] . Wout[d,:])
  // tiles 64m x 4n; XCD sub-grid 8m x 4n
  gemm_kernel<0, 2><<<dim3(32, 8, 1), 512, 0, stream>>>(
      cat, nullptr, 0L, 2048L, Wo, nullptr, 0L, 2048L,
      (void*)out0, 0L, 0L, nullptr, nullptr, 2048, 8, 4, 8);

  (void)in_sizes; (void)n_in; (void)out_size; (void)ws_size;
}